// Round 1
// 198.063 us; speedup vs baseline: 1.0002x; 1.0002x over previous
//
#include <hip/hip_runtime.h>
#include <stdint.h>

// ---------------------------------------------------------------------------
// Fused RBF histogram:  hist[o,i] = sum_n exp(-||x_n - c_o||^2 / 2) * x[n,i]
// N=524288, IN=64, OUT=128.  fp32 in/out.
//
// R13: kill the workspace. rocprof showed the timed graph dominated by
// ~77.8us x2 fillBufferAligned dispatches, each writing 512 MiB — the
// harness re-poisoning the FULL workspace allocation every iteration
// because kernel_launch used d_ws. Our own dispatches sum to <84us while
// dur_us=198. Fix: never touch d_ws. Epilogue goes through the existing
// atomicAdd path (512 blocks x 8192 disjoint-o fp32 atomics = 16.8MB of
// atomic traffic to a 32KB L2-resident output — same bytes the ws-write
// path paid, minus the reduce pass, minus the poison).
//  - core loop unchanged from R12 (R8/R11-verified): fp16 MFMA32 scores
//    with c*log2e RNE, P-in-registers C/D==A-frag identity, transpose-MFMA,
//    exp2 +38 bias, RTZ P-pack (absmax 2.9e-11 measured, 3.8x margin).
//  - grid 512 (2 blocks/CU), NITER 32 — residency unchanged.
// ---------------------------------------------------------------------------

typedef _Float16 half8v __attribute__((ext_vector_type(8)));
typedef _Float16 half4v __attribute__((ext_vector_type(4)));
typedef __fp16  fp16x2 __attribute__((ext_vector_type(2)));
typedef float floatx4 __attribute__((ext_vector_type(4)));

#define GRIDN 512        // 2 blocks/CU x 256 CUs
#define NITER 32         // 16384 32-row strips / 512 blocks
#define LOG2E 1.4426950408889634f
#define PBIAS 38.0f                       // P scaled by 2^38 into fp16 range
#define PUNSCALE 3.637978807091713e-12f   // 2^-38 (exact power of two)

#if __has_builtin(__builtin_amdgcn_exp2f)
#define EXP2F(x) __builtin_amdgcn_exp2f(x)
#else
#define EXP2F(x) exp2f(x)
#endif

// pack two fp32 -> fp16x2, RTZ (1 inst v_cvt_pkrtz_f16_f32)
static __device__ __forceinline__ unsigned int pk16z(float a, float b) {
  fp16x2 h = __builtin_amdgcn_cvt_pkrtz(a, b);
  return __builtin_bit_cast(unsigned int, h);
}
// pack two fp32 -> fp16x2, RNE — for x and c (their quantization dominates)
static __device__ __forceinline__ unsigned int pk16(float a, float b) {
  unsigned short ha = __builtin_bit_cast(unsigned short, (_Float16)a);
  unsigned short hb = __builtin_bit_cast(unsigned short, (_Float16)b);
  return (unsigned int)ha | ((unsigned int)hb << 16);
}
static __device__ __forceinline__ half4v mkh4(unsigned int lo, unsigned int hi) {
  uint2 u{lo, hi};
  return __builtin_bit_cast(half4v, u);
}
static __device__ __forceinline__ half8v mkh8(unsigned int a, unsigned int b,
                                              unsigned int c, unsigned int d) {
  uint4 u{a, b, c, d};
  return __builtin_bit_cast(half8v, u);
}

static __device__ __forceinline__ floatx4 mfma32(half8v a, half8v b, floatx4 c) {
  return __builtin_amdgcn_mfma_f32_16x16x32_f16(a, b, c, 0, 0, 0);
}
static __device__ __forceinline__ floatx4 mfma16(half4v a, half4v b, floatx4 c) {
  return __builtin_amdgcn_mfma_f32_16x16x16f16(a, b, c, 0, 0, 0);
}

// sXh row stride 72 shorts = 144 B: 16B-aligned rows, bank step 4 words
// -> <=2-way conflicts on b128/b64 frag reads (free per m136).
#define LSTR 72

__global__ __launch_bounds__(256, 4) void rbf_hist_kernel(
    const float* __restrict__ x, const float* __restrict__ c,
    float* __restrict__ out) {
  __shared__ unsigned short sXh[32][LSTR];  // fp16(x) strip, row-major [n][i]
  __shared__ float          sX2[32];        // -0.5*log2e*||x_n||^2 (fp32 exact)

  const int t    = threadIdx.x;    // 0..255
  const int lane = t & 63;
  const int w    = t >> 6;         // wave 0..3; owns o-tiles {2w, 2w+1}
  const int l15  = lane & 15;
  const int quad = lane >> 4;

  // ---- one-time: c*log2e fp16 (RNE) fragments for this wave's 2 o-tiles ----
  half8v chi[2][2];
  float m2c[2];                    // -0.5*log2e*||c_o||^2 + PBIAS
#pragma unroll
  for (int oo = 0; oo < 2; ++oo) {
    const int ot = 2 * w + oo;
    float sq = 0.f;
#pragma unroll
    for (int s = 0; s < 2; ++s) {
      const float* p = c + (ot * 16 + l15) * 64 + s * 32 + quad * 8;
      float4 va = *(const float4*)(p);
      float4 vb = *(const float4*)(p + 4);
      float f[8] = {va.x, va.y, va.z, va.w, vb.x, vb.y, vb.z, vb.w};
      unsigned int h[4];
#pragma unroll
      for (int jp = 0; jp < 4; ++jp) {
        float a = f[2 * jp], b = f[2 * jp + 1];
        sq = fmaf(a, a, sq);
        sq = fmaf(b, b, sq);
        h[jp] = pk16(a * LOG2E, b * LOG2E);   // RNE
      }
      chi[oo][s] = mkh8(h[0], h[1], h[2], h[3]);
    }
    sq += __shfl_xor(sq, 16);
    sq += __shfl_xor(sq, 32);
    m2c[oo] = fmaf(-0.5f * LOG2E, sq, PBIAS);
  }

  // identity B-frag for the transpose MFMA: I[k=quad*4+j][col=l15]
  half4v iden;
  {
    float e0 = (quad * 4 + 0 == l15) ? 1.f : 0.f;
    float e1 = (quad * 4 + 1 == l15) ? 1.f : 0.f;
    float e2 = (quad * 4 + 2 == l15) ? 1.f : 0.f;
    float e3 = (quad * 4 + 3 == l15) ? 1.f : 0.f;
    iden = mkh4(pk16z(e0, e1), pk16z(e2, e3));  // exact
  }

  // persistent histogram accumulators: 2 o-tiles x 4 i-tiles (scaled 2^38)
  floatx4 hacc[2][4];
#pragma unroll
  for (int a = 0; a < 2; ++a)
#pragma unroll
    for (int b = 0; b < 4; ++b) {
      floatx4 z = {0.f, 0.f, 0.f, 0.f};
      hacc[a][b] = z;
    }

  // staging map: thread t -> row r=t>>3 (0..31), cols q*8 .. q*8+7 (q=t&7)
  const int r = t >> 3, q = t & 7;

  // 2-deep prefetch ring: vA holds even strips, vB odd strips.
  float4 vA[2], vB[2];
  {
    const float* pA = x + ((size_t)blockIdx.x * 32 + r) * 64 + q * 8;
    vA[0] = *(const float4*)(pA);
    vA[1] = *(const float4*)(pA + 4);
    const float* pB =
        x + ((size_t)(blockIdx.x + GRIDN) * 32 + r) * 64 + q * 8;
    vB[0] = *(const float4*)(pB);
    vB[1] = *(const float4*)(pB + 4);
  }

#pragma unroll 1
  for (int it = 0; it < NITER; it += 2) {
#pragma unroll
    for (int par = 0; par < 2; ++par) {
      float4* v = (par == 0) ? vA : vB;

      __syncthreads();  // prev strip's sXh reads done -> safe to overwrite

      // ---- staging: fp16 RNE convert -> LDS row-major + exact fp32 x2 ----
      {
        float f0 = v[0].x, f1 = v[0].y, f2 = v[0].z, f3 = v[0].w;
        float f4 = v[1].x, f5 = v[1].y, f6 = v[1].z, f7 = v[1].w;
        float sq = 0.f;
        sq = fmaf(f0, f0, sq); sq = fmaf(f1, f1, sq);
        sq = fmaf(f2, f2, sq); sq = fmaf(f3, f3, sq);
        sq = fmaf(f4, f4, sq); sq = fmaf(f5, f5, sq);
        sq = fmaf(f6, f6, sq); sq = fmaf(f7, f7, sq);
        *(uint4*)&sXh[r][q * 8] =
            uint4{pk16(f0, f1), pk16(f2, f3), pk16(f4, f5), pk16(f6, f7)};
        // threads 8r..8r+7 (same wave) share row r
        sq += __shfl_xor(sq, 1);
        sq += __shfl_xor(sq, 2);
        sq += __shfl_xor(sq, 4);
        if (q == 0) sX2[r] = -0.5f * LOG2E * sq;
      }
      __syncthreads();  // strip ready

      // prefetch strip it+par+2 into this parity's buffer (issued after the
      // barrier — R5 lesson; lands during ~2 compute phases)
      if (it + par + 2 < NITER) {
        const float* p = x +
            ((size_t)(blockIdx.x + (it + par + 2) * GRIDN) * 32 + r) * 64 +
            q * 8;
        v[0] = *(const float4*)(p);
        v[1] = *(const float4*)(p + 4);
      }

      // ---- per 16-row sub-tile: scores -> exp2 -> P -> transpose -> hist ----
#pragma unroll
      for (int t2 = 0; t2 < 2; ++t2) {
        half8v xh0 = *(const half8v*)&sXh[t2 * 16 + l15][quad * 8];
        half8v xh1 = *(const half8v*)&sXh[t2 * 16 + l15][32 + quad * 8];
        float4 m2x = *(const float4*)&sX2[t2 * 16 + quad * 4];

        // stage A: 2 MFMAs per o-tile (fp16 x * fp16 c, both RNE)
        half4v P[2];
#pragma unroll
        for (int oo = 0; oo < 2; ++oo) {
          floatx4 acc = {m2x.x + m2c[oo], m2x.y + m2c[oo],
                         m2x.z + m2c[oo], m2x.w + m2c[oo]};
          acc = mfma32(xh0, chi[oo][0], acc);
          acc = mfma32(xh1, chi[oo][1], acc);
          // acc == log2e*(-d/2) + 38 ; C-frag == K=16 A-frag (R8-verified)
          P[oo] = mkh4(pk16z(EXP2F(acc[0]), EXP2F(acc[1])),
                       pk16z(EXP2F(acc[2]), EXP2F(acc[3])));  // RTZ, 1 inst
        }

        // transpose x via MFMA identity (R8-verified): b64 row-major reads
        half4v XT[4];
#pragma unroll
        for (int itl = 0; itl < 4; ++itl) {
          half4v ax = *(const half4v*)&sXh[t2 * 16 + l15][itl * 16 + quad * 4];
          floatx4 z = {0.f, 0.f, 0.f, 0.f};
          floatx4 d = mfma16(ax, iden, z);
          XT[itl] = mkh4(pk16z(d[0], d[1]), pk16z(d[2], d[3]));  // exact
        }

        // stage B: hist += P * X^T (K=16)
#pragma unroll
        for (int oo = 0; oo < 2; ++oo)
#pragma unroll
          for (int itl = 0; itl < 4; ++itl)
            hacc[oo][itl] = mfma16(P[oo], XT[itl], hacc[oo][itl]);
      }
    }
  }

  // ---- epilogue (unscale by 2^-38, exact): direct device-scope atomics ----
  // D: i = itl*16 + l15, o = (2w+oo)*16 + quad*4 + e
  // 8192 disjoint elements per block (waves own disjoint o) -> one atomic
  // per element per block; 512 updates/address to a 32KB L2-resident out.
#pragma unroll
  for (int oo = 0; oo < 2; ++oo)
#pragma unroll
    for (int itl = 0; itl < 4; ++itl)
#pragma unroll
      for (int e = 0; e < 4; ++e) {
        int o = (2 * w + oo) * 16 + quad * 4 + e;
        int i = itl * 16 + l15;
        atomicAdd(out + o * 64 + i, hacc[oo][itl][e] * PUNSCALE);
      }
}

__global__ void zero_out_kernel(float* out, int n) {
  int i = blockIdx.x * 256 + threadIdx.x;
  if (i < n) out[i] = 0.f;
}

extern "C" void kernel_launch(void* const* d_in, const int* in_sizes, int n_in,
                              void* d_out, int out_size, void* d_ws, size_t ws_size,
                              hipStream_t stream) {
  (void)in_sizes; (void)n_in; (void)d_ws; (void)ws_size;
  const float* x = (const float*)d_in[0];        // [524288, 64]
  const float* c = (const float*)d_in[1];        // [128, 64]
  float* out = (float*)d_out;                    // [128, 64]

  zero_out_kernel<<<(out_size + 255) / 256, 256, 0, stream>>>(out, out_size);
  rbf_hist_kernel<<<GRIDN, 256, 0, stream>>>(x, c, out);
}